// Round 1
// baseline (1441.058 us; speedup 1.0000x reference)
//
#include <hip/hip_runtime.h>

// GBDT split histogram + cumsum.
// X: [N=1e6, F=100] int32 bins in [0,256); gradient, hessian: [N] f32.
// out = concat(Gl[1,F,256], Hl[1,F,256]) where Gl[f,b] = sum_i g[i]*(X[i,f] <= b).
//
// Strategy:
//  K1: grid = NG*C blocks. Each block owns FG=20 features (NG=5 groups tile the
//      100-feature row; group byte-span 80 B, 16B-aligned since row stride is
//      400 B) and a row chunk. Privatized LDS histograms (2*20*256 f32 = 41 KB,
//      3 blocks/CU), ds_add_f32 atomics, deterministic partial write to d_ws.
//  K2: 2*F blocks x 256 threads: reduce C partials per (which, feature, bin),
//      inclusive scan over bins in LDS, write out.

#define F     100
#define FG    20
#define NG    5
#define BINS  256
#define TPB   256
#define CMAX  152   // 5*152 = 760 blocks ~= 3 per CU at 41 KB LDS

__global__ __launch_bounds__(TPB) void hist_part_kernel(
    const int* __restrict__ X, const float* __restrict__ grad,
    const float* __restrict__ hess, float* __restrict__ part,
    int N, int rows_per_chunk)
{
    __shared__ float hist[2 * FG * BINS];   // 40960 B: [0]=grad plane, [1]=hess plane
    const int tid = threadIdx.x;
    const int c   = blockIdx.x / NG;        // row chunk
    const int grp = blockIdx.x % NG;        // feature group
    const int col0 = grp * FG;

    for (int i = tid; i < 2 * FG * BINS; i += TPB) hist[i] = 0.0f;
    __syncthreads();

    int r0 = c * rows_per_chunk;
    int r1 = r0 + rows_per_chunk;
    if (r1 > N) r1 = N;

    for (int r = r0 + tid; r < r1; r += TPB) {
        float gv = grad[r];
        float hv = hess[r];
        // 80 B segment, 16B-aligned: 5x dwordx4 gathers
        const int4* p = reinterpret_cast<const int4*>(X + (size_t)r * F + col0);
        int4 v0 = p[0], v1 = p[1], v2 = p[2], v3 = p[3], v4 = p[4];
        int bins[FG] = {v0.x, v0.y, v0.z, v0.w,
                        v1.x, v1.y, v1.z, v1.w,
                        v2.x, v2.y, v2.z, v2.w,
                        v3.x, v3.y, v3.z, v3.w,
                        v4.x, v4.y, v4.z, v4.w};
#pragma unroll
        for (int f = 0; f < FG; f++) {
            int b = bins[f];
            atomicAdd(&hist[f * BINS + b], gv);                 // ds_add_f32
            atomicAdd(&hist[FG * BINS + f * BINS + b], hv);
        }
    }
    __syncthreads();

    // part layout: part[((c*2 + which)*F + fglobal)*BINS + b]
    float* dst_g = part + ((size_t)(c * 2 + 0) * F + col0) * BINS;
    float* dst_h = part + ((size_t)(c * 2 + 1) * F + col0) * BINS;
    for (int i = tid; i < FG * BINS; i += TPB) {
        dst_g[i] = hist[i];
        dst_h[i] = hist[FG * BINS + i];
    }
}

__global__ __launch_bounds__(TPB) void reduce_scan_kernel(
    const float* __restrict__ part, float* __restrict__ out, int C)
{
    __shared__ float s[BINS];
    const int b = threadIdx.x;
    const int f = blockIdx.x % F;
    const int w = blockIdx.x / F;   // 0 = grad (Gl), 1 = hess (Hl)

    float acc = 0.0f;
    const float* src = part + ((size_t)w * F + f) * BINS + b;
    const size_t cstride = (size_t)2 * F * BINS;
    for (int c = 0; c < C; c++) acc += src[(size_t)c * cstride];

    s[b] = acc;
    __syncthreads();
    // Hillis-Steele inclusive scan over 256 bins
#pragma unroll
    for (int off = 1; off < BINS; off <<= 1) {
        float t = (b >= off) ? s[b - off] : 0.0f;
        __syncthreads();
        s[b] += t;
        __syncthreads();
    }
    out[((size_t)w * F + f) * BINS + b] = s[b];
}

extern "C" void kernel_launch(void* const* d_in, const int* in_sizes, int n_in,
                              void* d_out, int out_size, void* d_ws, size_t ws_size,
                              hipStream_t stream)
{
    const int*   X = (const int*)d_in[0];
    const float* g = (const float*)d_in[1];
    const float* h = (const float*)d_in[2];
    float* out  = (float*)d_out;
    float* part = (float*)d_ws;
    const int N = in_sizes[1];   // 1e6 samples (in_sizes[0] = N*F)

    const size_t chunk_bytes = (size_t)2 * F * BINS * sizeof(float);  // 204800
    int C = (int)(ws_size / chunk_bytes);
    if (C > CMAX) C = CMAX;
    if (C < 1)    C = 1;
    const int rpc = (N + C - 1) / C;

    hipLaunchKernelGGL(hist_part_kernel, dim3(NG * C), dim3(TPB), 0, stream,
                       X, g, h, part, N, rpc);
    hipLaunchKernelGGL(reduce_scan_kernel, dim3(2 * F), dim3(TPB), 0, stream,
                       part, out, C);
}

// Round 2
// 1396.893 us; speedup vs baseline: 1.0316x; 1.0316x over previous
//
#include <hip/hip_runtime.h>

// GBDT split histogram + cumsum.
// X: [N=1e6, F=100] int32 bins in [0,256); gradient, hessian: [N] f32.
// out = concat(Gl[1,F,256], Hl[1,F,256]) where Gl[f,b] = sum_i g[i]*(X[i,f] <= b).
//
// R1 -> R2: latency-bound fix.
//  K1: thread t -> (q=t/5, s=t%5): 5 consecutive lanes read the 5 int4s of one
//      row's 80 B feature-group segment -> near-contiguous wave loads
//      (~26 lines/wave-op vs 64 with the per-thread-row map). 512-thread
//      blocks (8 waves) x 41 KB LDS -> 3 blocks/CU = 24 waves/CU. One-deep
//      register prefetch of next row's int4 + g + h.
//  K2: 1024 threads/block, 4 slices x 4 accumulators -> 16-deep MLP.

#define F     100
#define FG    20     // features per block (group)
#define NG    5      // groups tiling the 100-feature row
#define BINS  256
#define TPB   512
#define RPI   (TPB / 5)       // 102 rows per block-iteration
#define CMAX  152             // 5*152 = 760 blocks ~= 3/CU

__global__ __launch_bounds__(TPB) void hist_part_kernel(
    const int* __restrict__ X, const float* __restrict__ grad,
    const float* __restrict__ hess, float* __restrict__ part,
    int N, int rows_per_chunk)
{
    __shared__ float hist[2 * FG * BINS];   // 40960 B: grad plane, hess plane
    const int tid = threadIdx.x;
    const int c    = blockIdx.x / NG;
    const int grp  = blockIdx.x % NG;
    const int col0 = grp * FG;

    for (int i = tid; i < 2 * FG * BINS; i += TPB) hist[i] = 0.0f;
    __syncthreads();

    int r0 = c * rows_per_chunk;
    int r1 = r0 + rows_per_chunk;
    if (r1 > N) r1 = N;

    const int s = tid % 5;        // which int4 of the 80 B segment
    const int q = tid / 5;        // row-within-tile, [0,102] (102 -> inactive)

    if (q < RPI) {
        const int fb0 = (4 * s) * BINS;           // grad-plane base for f=4s
        const int fb1 = FG * BINS + fb0;          // hess-plane base
        const char* xb = (const char*)(X + col0 + 4 * s);

        int r = r0 + q;
        if (r < r1) {
            int4  cur = *(const int4*)(xb + (size_t)r * (F * 4));
            float gc = grad[r], hc = hess[r];
            for (int rn = r + RPI; rn < r1; rn += RPI) {
                int4  nxt = *(const int4*)(xb + (size_t)rn * (F * 4));
                float gn = grad[rn], hn = hess[rn];
                atomicAdd(&hist[fb0 + 0 * BINS + cur.x], gc);
                atomicAdd(&hist[fb1 + 0 * BINS + cur.x], hc);
                atomicAdd(&hist[fb0 + 1 * BINS + cur.y], gc);
                atomicAdd(&hist[fb1 + 1 * BINS + cur.y], hc);
                atomicAdd(&hist[fb0 + 2 * BINS + cur.z], gc);
                atomicAdd(&hist[fb1 + 2 * BINS + cur.z], hc);
                atomicAdd(&hist[fb0 + 3 * BINS + cur.w], gc);
                atomicAdd(&hist[fb1 + 3 * BINS + cur.w], hc);
                cur = nxt; gc = gn; hc = hn;
            }
            atomicAdd(&hist[fb0 + 0 * BINS + cur.x], gc);
            atomicAdd(&hist[fb1 + 0 * BINS + cur.x], hc);
            atomicAdd(&hist[fb0 + 1 * BINS + cur.y], gc);
            atomicAdd(&hist[fb1 + 1 * BINS + cur.y], hc);
            atomicAdd(&hist[fb0 + 2 * BINS + cur.z], gc);
            atomicAdd(&hist[fb1 + 2 * BINS + cur.z], hc);
            atomicAdd(&hist[fb0 + 3 * BINS + cur.w], gc);
            atomicAdd(&hist[fb1 + 3 * BINS + cur.w], hc);
        }
    }
    __syncthreads();

    // part[((c*2 + which)*F + fglobal)*BINS + b]
    float* dst_g = part + ((size_t)(c * 2 + 0) * F + col0) * BINS;
    float* dst_h = part + ((size_t)(c * 2 + 1) * F + col0) * BINS;
    for (int i = tid; i < FG * BINS; i += TPB) {
        dst_g[i] = hist[i];
        dst_h[i] = hist[FG * BINS + i];
    }
}

#define K2TPB 1024

__global__ __launch_bounds__(K2TPB) void reduce_scan_kernel(
    const float* __restrict__ part, float* __restrict__ out, int C)
{
    __shared__ float s4[4 * BINS];
    __shared__ float s[BINS];
    const int tid   = threadIdx.x;
    const int b     = tid & (BINS - 1);
    const int slice = tid >> 8;           // 0..3
    const int f = blockIdx.x % F;
    const int w = blockIdx.x / F;         // 0 = Gl, 1 = Hl

    const size_t cstride = (size_t)2 * F * BINS;
    const float* src = part + ((size_t)w * F + f) * BINS + b;

    float a0 = 0.f, a1 = 0.f, a2 = 0.f, a3 = 0.f;
    int c = slice;
    for (; c + 12 < C; c += 16) {
        a0 += src[(size_t)(c     ) * cstride];
        a1 += src[(size_t)(c +  4) * cstride];
        a2 += src[(size_t)(c +  8) * cstride];
        a3 += src[(size_t)(c + 12) * cstride];
    }
    for (; c < C; c += 4) a0 += src[(size_t)c * cstride];

    s4[slice * BINS + b] = a0 + a1 + a2 + a3;
    __syncthreads();
    if (slice == 0)
        s[b] = s4[b] + s4[BINS + b] + s4[2 * BINS + b] + s4[3 * BINS + b];
    __syncthreads();

    // Hillis-Steele inclusive scan over 256 bins (slice 0 active; all threads barrier)
#pragma unroll
    for (int off = 1; off < BINS; off <<= 1) {
        float t = 0.f;
        if (slice == 0 && b >= off) t = s[b - off];
        __syncthreads();
        if (slice == 0) s[b] += t;
        __syncthreads();
    }
    if (slice == 0)
        out[((size_t)w * F + f) * BINS + b] = s[b];
}

extern "C" void kernel_launch(void* const* d_in, const int* in_sizes, int n_in,
                              void* d_out, int out_size, void* d_ws, size_t ws_size,
                              hipStream_t stream)
{
    const int*   X = (const int*)d_in[0];
    const float* g = (const float*)d_in[1];
    const float* h = (const float*)d_in[2];
    float* out  = (float*)d_out;
    float* part = (float*)d_ws;
    const int N = in_sizes[1];

    const size_t chunk_bytes = (size_t)2 * F * BINS * sizeof(float);  // 204800
    int C = (int)(ws_size / chunk_bytes);
    if (C > CMAX) C = CMAX;
    if (C < 1)    C = 1;
    const int rpc = (N + C - 1) / C;

    hipLaunchKernelGGL(hist_part_kernel, dim3(NG * C), dim3(TPB), 0, stream,
                       X, g, h, part, N, rpc);
    hipLaunchKernelGGL(reduce_scan_kernel, dim3(2 * F), dim3(K2TPB), 0, stream,
                       part, out, C);
}

// Round 4
// 573.315 us; speedup vs baseline: 2.5136x; 2.4365x over previous
//
#include <hip/hip_runtime.h>

// GBDT split histogram + cumsum.
// X: [N=1e6, F=100] int32 bins in [0,256); gradient, hessian: [N] f32.
// out = concat(Gl[1,F,256], Hl[1,F,256]), Gl[f,b] = sum_i g[i]*(X[i,f] <= b).
//
// R3: LDS atomic unit is lane-op-rate bound (~3.1 cyc/lane-op; R1==R2 with
// equal atomic counts, all pipes idle). Halve lane-ops with fixed-point u64
// packing: one ds_add_u64 carries both g (hi32, s32 @2^20) and h (lo32, u32
// @2^20) per (row,feature): 2e8 -> 1e8 lane-atomics. Integer adds are exact
// and commutative -> blocks flush LDS hist via global u64 atomicAdd into a
// single device-wide accumulator (deterministic), killing the chunk-partials
// pass (R2's K2 was 388 us of latency-bound strided reads).

#define F     100
#define FG    20      // features per block group
#define NG    5       // groups tiling the 100-feature row (80 B, int4-clean)
#define BINS  256
#define TPB   512
#define RPI   (TPB / 5)     // 102 rows per block-iteration
#define CCHUNKS 152         // 5*152 = 760 blocks
#define SCALE_F 1048576.0f  // 2^20
#define INV_SCALE (1.0 / 1048576.0)

__global__ __launch_bounds__(512) void zero_kernel(unsigned long long* __restrict__ p)
{
    int i = blockIdx.x * 512 + threadIdx.x;
    if (i < 2 * F * BINS) p[i] = 0ULL;
}

__global__ __launch_bounds__(TPB) void hist_part_kernel(
    const int* __restrict__ X, const float* __restrict__ grad,
    const float* __restrict__ hess, unsigned long long* __restrict__ acc,
    int N, int rows_per_chunk)
{
    // hi32 = sum g*2^20 (wraps as s32), lo32 = sum h*2^20 (u32, no carry-out)
    __shared__ unsigned long long hist[FG * BINS];   // 40960 B -> 3 blocks/CU
    const int tid  = threadIdx.x;
    const int c    = blockIdx.x / NG;
    const int grp  = blockIdx.x % NG;
    const int col0 = grp * FG;

    for (int i = tid; i < FG * BINS; i += TPB) hist[i] = 0ULL;
    __syncthreads();

    int r0 = c * rows_per_chunk;
    int r1 = r0 + rows_per_chunk;
    if (r1 > N) r1 = N;

    const int s = tid % 5;        // which int4 of the 80 B segment
    const int q = tid / 5;        // row-within-tile

    if (q < RPI) {
        const int fb = (4 * s) * BINS;   // plane base for features 4s..4s+3
        const char* xb = (const char*)(X + col0 + 4 * s);

        int r = r0 + q;
        if (r < r1) {
            int4 cur = *(const int4*)(xb + (size_t)r * (F * 4));
            int  gq  = __float2int_rn(grad[r] * SCALE_F);
            int  hq  = __float2int_rn(hess[r] * SCALE_F);
            unsigned long long vc =
                ((unsigned long long)(unsigned int)gq << 32) | (unsigned int)hq;
            for (int rn = r + RPI; rn < r1; rn += RPI) {
                int4 nxt = *(const int4*)(xb + (size_t)rn * (F * 4));
                int  gn  = __float2int_rn(grad[rn] * SCALE_F);
                int  hn  = __float2int_rn(hess[rn] * SCALE_F);
                unsigned long long vn =
                    ((unsigned long long)(unsigned int)gn << 32) | (unsigned int)hn;
                atomicAdd(&hist[fb + 0 * BINS + cur.x], vc);
                atomicAdd(&hist[fb + 1 * BINS + cur.y], vc);
                atomicAdd(&hist[fb + 2 * BINS + cur.z], vc);
                atomicAdd(&hist[fb + 3 * BINS + cur.w], vc);
                cur = nxt; vc = vn;
            }
            atomicAdd(&hist[fb + 0 * BINS + cur.x], vc);
            atomicAdd(&hist[fb + 1 * BINS + cur.y], vc);
            atomicAdd(&hist[fb + 2 * BINS + cur.z], vc);
            atomicAdd(&hist[fb + 3 * BINS + cur.w], vc);
        }
    }
    __syncthreads();

    // Flush: split fields into separate global i64 accumulators (exact).
    // acc layout: g64[F*BINS] then h64[F*BINS]; index = col0*BINS + i.
    unsigned long long* g64 = acc;
    unsigned long long* h64 = acc + (size_t)F * BINS;
    for (int i = tid; i < FG * BINS; i += TPB) {
        unsigned long long v = hist[i];
        long long gi = (long long)(int)(v >> 32);            // sign-extend
        unsigned long long hi = (unsigned long long)(unsigned int)v;
        atomicAdd(&g64[col0 * BINS + i], (unsigned long long)gi);
        atomicAdd(&h64[col0 * BINS + i], hi);
    }
}

__global__ __launch_bounds__(BINS) void scan_kernel(
    const unsigned long long* __restrict__ acc, float* __restrict__ out)
{
    __shared__ float sv[BINS];
    const int b = threadIdx.x;
    const int f = blockIdx.x % F;
    const int w = blockIdx.x / F;   // 0 = Gl (g plane), 1 = Hl (h plane)

    unsigned long long v = acc[(size_t)w * F * BINS + (size_t)f * BINS + b];
    sv[b] = (float)((double)(long long)v * INV_SCALE);
    __syncthreads();
#pragma unroll
    for (int off = 1; off < BINS; off <<= 1) {
        float t = (b >= off) ? sv[b - off] : 0.0f;
        __syncthreads();
        sv[b] += t;
        __syncthreads();
    }
    out[((size_t)w * F + f) * BINS + b] = sv[b];
}

extern "C" void kernel_launch(void* const* d_in, const int* in_sizes, int n_in,
                              void* d_out, int out_size, void* d_ws, size_t ws_size,
                              hipStream_t stream)
{
    const int*   X = (const int*)d_in[0];
    const float* g = (const float*)d_in[1];
    const float* h = (const float*)d_in[2];
    float*              out = (float*)d_out;
    unsigned long long* acc = (unsigned long long*)d_ws;   // 2*F*BINS u64 = 409600 B
    const int N = in_sizes[1];

    const int C   = CCHUNKS;
    const int rpc = (N + C - 1) / C;

    hipLaunchKernelGGL(zero_kernel, dim3((2 * F * BINS + 511) / 512), dim3(512),
                       0, stream, acc);
    hipLaunchKernelGGL(hist_part_kernel, dim3(NG * C), dim3(TPB), 0, stream,
                       X, g, h, acc, N, rpc);
    hipLaunchKernelGGL(scan_kernel, dim3(2 * F), dim3(BINS), 0, stream,
                       acc, out);
}

// Round 5
// 570.125 us; speedup vs baseline: 2.5276x; 1.0056x over previous
//
#include <hip/hip_runtime.h>

// GBDT split histogram + cumsum.
// X: [N=1e6, F=100] int32 bins in [0,256); gradient, hessian: [N] f32.
// out = concat(Gl[1,F,256], Hl[1,F,256]), Gl[f,b] = sum_i g[i]*(X[i,f] <= b).
//
// R4 -> R5: K1 is LDS-atomic-op-rate bound (~1.13 cyc/lane-op vs ~1.0 floor;
// 1e8 ds_add_u64, all other pipes idle). Only lever left: wave supply.
// TPB 512 -> 1024 (16 waves/block) x 40 KB LDS -> exactly 2 blocks/CU = 32
// waves = 100% occupancy (R4 reported 48.5%). Grid = 510 blocks = exact
// 2-per-CU tiling, no tail. Fixed-point u64 packing unchanged:
// one ds_add_u64 carries g (hi32, s32 @2^20) and h (lo32, u32 @2^20);
// integer adds exact+commutative -> flush via global u64 atomicAdd
// (deterministic); f32 conversion + cumsum in K2.
// Timed-region budget: ~376 us harness restore/poison (d_ws 1.6 GB fill +
// d_in 400 MB copy) + K1 + ~12 us (zero + scan).

#define F     100
#define FG    20      // features per block group
#define NG    5       // groups tiling the 100-feature row (80 B, int4-clean)
#define BINS  256
#define TPB   1024
#define RPI   (TPB / 5)     // 204 rows per block-iteration (threads 1020-1023 idle)
#define CCHUNKS 102         // 5*102 = 510 blocks = 2 per CU exactly
#define SCALE_F 1048576.0f  // 2^20
#define INV_SCALE (1.0 / 1048576.0)

__global__ __launch_bounds__(512) void zero_kernel(unsigned long long* __restrict__ p)
{
    int i = blockIdx.x * 512 + threadIdx.x;
    if (i < 2 * F * BINS) p[i] = 0ULL;
}

__global__ __launch_bounds__(TPB) void hist_part_kernel(
    const int* __restrict__ X, const float* __restrict__ grad,
    const float* __restrict__ hess, unsigned long long* __restrict__ acc,
    int N, int rows_per_chunk)
{
    // hi32 = sum g*2^20 (wraps as s32), lo32 = sum h*2^20 (u32, no carry-out)
    __shared__ unsigned long long hist[FG * BINS];   // 40960 B -> 2 blocks/CU
    const int tid  = threadIdx.x;
    const int c    = blockIdx.x / NG;
    const int grp  = blockIdx.x % NG;
    const int col0 = grp * FG;

    for (int i = tid; i < FG * BINS; i += TPB) hist[i] = 0ULL;
    __syncthreads();

    int r0 = c * rows_per_chunk;
    int r1 = r0 + rows_per_chunk;
    if (r1 > N) r1 = N;

    const int s = tid % 5;        // which int4 of the 80 B segment
    const int q = tid / 5;        // row-within-tile

    if (q < RPI) {
        const int fb = (4 * s) * BINS;   // plane base for features 4s..4s+3
        const char* xb = (const char*)(X + col0 + 4 * s);

        int r = r0 + q;
        if (r < r1) {
            int4 cur = *(const int4*)(xb + (size_t)r * (F * 4));
            int  gq  = __float2int_rn(grad[r] * SCALE_F);
            int  hq  = __float2int_rn(hess[r] * SCALE_F);
            unsigned long long vc =
                ((unsigned long long)(unsigned int)gq << 32) | (unsigned int)hq;
            for (int rn = r + RPI; rn < r1; rn += RPI) {
                int4 nxt = *(const int4*)(xb + (size_t)rn * (F * 4));
                int  gn  = __float2int_rn(grad[rn] * SCALE_F);
                int  hn  = __float2int_rn(hess[rn] * SCALE_F);
                unsigned long long vn =
                    ((unsigned long long)(unsigned int)gn << 32) | (unsigned int)hn;
                atomicAdd(&hist[fb + 0 * BINS + cur.x], vc);
                atomicAdd(&hist[fb + 1 * BINS + cur.y], vc);
                atomicAdd(&hist[fb + 2 * BINS + cur.z], vc);
                atomicAdd(&hist[fb + 3 * BINS + cur.w], vc);
                cur = nxt; vc = vn;
            }
            atomicAdd(&hist[fb + 0 * BINS + cur.x], vc);
            atomicAdd(&hist[fb + 1 * BINS + cur.y], vc);
            atomicAdd(&hist[fb + 2 * BINS + cur.z], vc);
            atomicAdd(&hist[fb + 3 * BINS + cur.w], vc);
        }
    }
    __syncthreads();

    // Flush: split fields into separate global i64 accumulators (exact).
    // acc layout: g64[F*BINS] then h64[F*BINS]; index = col0*BINS + i.
    unsigned long long* g64 = acc;
    unsigned long long* h64 = acc + (size_t)F * BINS;
    for (int i = tid; i < FG * BINS; i += TPB) {
        unsigned long long v = hist[i];
        long long gi = (long long)(int)(v >> 32);            // sign-extend
        unsigned long long hi = (unsigned long long)(unsigned int)v;
        atomicAdd(&g64[col0 * BINS + i], (unsigned long long)gi);
        atomicAdd(&h64[col0 * BINS + i], hi);
    }
}

__global__ __launch_bounds__(BINS) void scan_kernel(
    const unsigned long long* __restrict__ acc, float* __restrict__ out)
{
    __shared__ float sv[BINS];
    const int b = threadIdx.x;
    const int f = blockIdx.x % F;
    const int w = blockIdx.x / F;   // 0 = Gl (g plane), 1 = Hl (h plane)

    unsigned long long v = acc[(size_t)w * F * BINS + (size_t)f * BINS + b];
    sv[b] = (float)((double)(long long)v * INV_SCALE);
    __syncthreads();
#pragma unroll
    for (int off = 1; off < BINS; off <<= 1) {
        float t = (b >= off) ? sv[b - off] : 0.0f;
        __syncthreads();
        sv[b] += t;
        __syncthreads();
    }
    out[((size_t)w * F + f) * BINS + b] = sv[b];
}

extern "C" void kernel_launch(void* const* d_in, const int* in_sizes, int n_in,
                              void* d_out, int out_size, void* d_ws, size_t ws_size,
                              hipStream_t stream)
{
    const int*   X = (const int*)d_in[0];
    const float* g = (const float*)d_in[1];
    const float* h = (const float*)d_in[2];
    float*              out = (float*)d_out;
    unsigned long long* acc = (unsigned long long*)d_ws;   // 2*F*BINS u64 = 409600 B
    const int N = in_sizes[1];

    const int C   = CCHUNKS;
    const int rpc = (N + C - 1) / C;

    hipLaunchKernelGGL(zero_kernel, dim3((2 * F * BINS + 511) / 512), dim3(512),
                       0, stream, acc);
    hipLaunchKernelGGL(hist_part_kernel, dim3(NG * C), dim3(TPB), 0, stream,
                       X, g, h, acc, N, rpc);
    hipLaunchKernelGGL(scan_kernel, dim3(2 * F), dim3(BINS), 0, stream,
                       acc, out);
}